// Round 1
// baseline (89.387 us; speedup 1.0000x reference)
//
#include <hip/hip_runtime.h>

// Problem constants (from setup_inputs):
//   b=1, n_l=4096, l=16, nh=1, nv=4, f=1, nh_sz=9, nt=16
//   n = 65536 fine points, K = 144 candidates/cell, rows = n_l*nt = 65536
#define N_L   4096
#define NT    16
#define NV    4
#define NHSZ  9
#define KCAND 144
#define MASKV 1.0e6f
#define CUT   0.01f
#define BIG   3.0e38f

// lexicographic (d, idx): true if (da,ia) ranks before (db,ib).
// Matches jax.lax.top_k's lowest-index-first tie-break.
__device__ __forceinline__ bool lex_lt(float da, int ia, float db, int ib) {
    return (da < db) || ((da == db) && (ia < ib));
}

// One block = 256 threads = 32 rows (8 lanes per row) = 2 coarse cells.
//   vs previous version (4 lanes/row, 1024 blocks = 4 waves/SIMD):
//   2048 blocks -> 8 blocks/CU -> 32 waves/CU (full occupancy), and the
//   per-lane serial top-3 insertion chain halves (36 -> 18/20 candidates).
__global__ __launch_bounds__(256, 8) void interp_kernel(
    const float* __restrict__ x,      // (65536 pts, 4 vars)
    const float* __restrict__ mask,   // (65536 pts, 4 vars)
    const float* __restrict__ dist,   // (65536 rows, 144)
    const int*   __restrict__ nh_idx, // (4096, 9)
    float*       __restrict__ out)    // (65536 rows, 4 vars)
{
    __shared__ int s_cells[2 * NHSZ]; // 2 local cells x 9 neighbor cell ids
    __shared__ int s_dirty[2];        // per local cell: any masked point in nbhd?

    const int t    = threadIdx.x;
    const int row0 = blockIdx.x * 32; // 32 rows per block
    const int c0   = row0 >> 4;       // 2 cells per block
    const int row  = row0 + (t >> 3);
    const int sub8 = t & 7;           // lane within the row-octet
    const int sub  = t & 3;           // variable owned in the epilogue
    const int lc   = t >> 7;          // local cell 0..1

    // Issue the row's 5 distance dwordx4 loads immediately (no dependencies)
    // so their HBM latency overlaps the neighbor-table load + mask scan.
    // Lane sub8 owns float4 chunks q = {sub8, sub8+8, sub8+16, sub8+24} and,
    // for sub8<4, q = 32+sub8 (lanes 4-7 fetch a duplicate and ignore it).
    const float4* dp = (const float4*)(dist + (size_t)row * KCAND);
    float4 cA = dp[sub8];
    float4 cB = dp[sub8 + 8];
    float4 cC = dp[sub8 + 16];
    float4 cD = dp[sub8 + 24];
    float4 cE = dp[32 + (sub8 & 3)];

    if (t < 2) s_dirty[t] = 0;
    if (t < 2 * NHSZ) s_cells[t] = nh_idx[c0 * NHSZ + t];
    __syncthreads();

    // Cooperative mask check: 18 neighbor entries x 64 mask words = 1152 floats.
    // (never fires on the bench input: mask == 0)
#pragma unroll
    for (int i = 0; i < 5; ++i) {
        int f = t + 256 * i;          // 0..1279, guard at 1152
        if (f < 2 * NHSZ * 64) {
            int e = f >> 6;           // neighbor entry 0..17
            int w = f & 63;           // word within cell's 64 mask floats
            float m = mask[s_cells[e] * 64 + w];
            if (m != 0.0f) atomicOr(&s_dirty[e / NHSZ], 1);
        }
    }
    __syncthreads();

    const int* cells = &s_cells[lc * NHSZ];

    if (s_dirty[lc] == 0) {
        // ---- fast path: selection shared across the 4 variables ----
        float d0 = BIG, d1 = BIG, d2 = BIG;
        int   i0 = 0,   i1 = 0,   i2 = 0;

        // Strict '<' insertion; per-lane k is scanned ascending, so ties
        // resolve lowest-index-first within the lane.
#define INS(dv, kv) do {                                                   \
            float d_ = (dv); int k_ = (kv);                                \
            bool c0_ = d_ < d0, c1_ = d_ < d1, c2_ = d_ < d2;              \
            d2 = c1_ ? d1 : (c2_ ? d_ : d2);                               \
            i2 = c1_ ? i1 : (c2_ ? k_ : i2);                               \
            d1 = c0_ ? d0 : (c1_ ? d_ : d1);                               \
            i1 = c0_ ? i0 : (c1_ ? k_ : i1);                               \
            d0 = c0_ ? d_ : d0;                                            \
            i0 = c0_ ? k_ : i0;                                            \
        } while (0)
#define INS4(c, q) do {                                                    \
            int kb_ = 4 * (q);                                             \
            INS((c).x, kb_ + 0); INS((c).y, kb_ + 1);                      \
            INS((c).z, kb_ + 2); INS((c).w, kb_ + 3);                      \
        } while (0)

        INS4(cA, sub8);
        INS4(cB, sub8 + 8);
        INS4(cC, sub8 + 16);
        INS4(cD, sub8 + 24);
        if (sub8 < 4) INS4(cE, 32 + sub8);
#undef INS4
#undef INS

        // Butterfly merge across the octet (xor 1, 2, 4); after all three
        // steps every lane of the octet holds the row's global top-3.
#pragma unroll
        for (int mm = 0; mm < 3; ++mm) {
            const int msk = 1 << mm;
            float ed0 = __shfl_xor(d0, msk);
            float ed1 = __shfl_xor(d1, msk);
            float ed2 = __shfl_xor(d2, msk);
            int   ei0 = __shfl_xor(i0, msk);
            int   ei1 = __shfl_xor(i1, msk);
            int   ei2 = __shfl_xor(i2, msk);
            // (3,3) merge network keeping smallest 3, lexicographic order:
            bool cA_ = lex_lt(d0, i0, ed0, ei0);
            float lo0d = cA_ ? d0 : ed0;  int lo0i = cA_ ? i0 : ei0;
            float hi0d = cA_ ? ed0 : d0;  int hi0i = cA_ ? ei0 : i0;
            bool cB_ = lex_lt(d1, i1, ed1, ei1);
            float lo1d = cB_ ? d1 : ed1;  int lo1i = cB_ ? i1 : ei1;
            float hi1d = cB_ ? ed1 : d1;  int hi1i = cB_ ? ei1 : i1;
            bool cC_ = lex_lt(d2, i2, ed2, ei2);
            float lo2d = cC_ ? d2 : ed2;  int lo2i = cC_ ? i2 : ei2;
            // r0 = lo0 ; r1 = min(hi0, lo1) ; r2 = min(max(hi0, lo1), lo2)
            bool cD_ = lex_lt(hi0d, hi0i, lo1d, lo1i);
            float r1d = cD_ ? hi0d : lo1d; int r1i = cD_ ? hi0i : lo1i;
            float t2d = cD_ ? lo1d : hi0d; int t2i = cD_ ? lo1i : hi0i;
            bool cE_ = lex_lt(t2d, t2i, lo2d, lo2i);
            float r2d = cE_ ? t2d : lo2d;  int r2i = cE_ ? t2i : lo2i;
            d0 = lo0d; i0 = lo0i;
            d1 = r1d;  i1 = r1i;
            d2 = r2d;  i2 = r2i;
        }

        // Epilogue: lanes 0-3 of each octet emit the 4 variables.
        if (sub8 < 4) {
            float v0 = fmaxf(d0, CUT), v1 = fmaxf(d1, CUT), v2 = fmaxf(d2, CUT);
            float w0 = 1.0f / (v0 * v0);
            float w1 = 1.0f / (v1 * v1);
            float w2 = 1.0f / (v2 * v2);
            float inv = 1.0f / (w0 + w1 + w2);
            int j0 = i0 >> 4, p0 = i0 & 15;
            int j1 = i1 >> 4, p1 = i1 & 15;
            int j2 = i2 >> 4, p2 = i2 & 15;
            float xa = x[cells[j0] * 64 + p0 * 4 + sub];
            float xb = x[cells[j1] * 64 + p1 * 4 + sub];
            float xd = x[cells[j2] * 64 + p2 * 4 + sub];
            out[row * 4 + sub] = (xa * w0 + xb * w1 + xd * w2) * inv;
        }
    } else {
        // ---- slow path (general mask semantics): one lane per (row,var)
        // scans its own variable's masked distances over all 144 candidates.
        if ((t & 4) == 0) {
            const float* dr = dist + (size_t)row * KCAND;
            float d0 = BIG, d1 = BIG, d2 = BIG;
            int   i0 = 0,   i1 = 0,   i2 = 0;
            for (int k = 0; k < KCAND; ++k) {
                int j = k >> 4, p = k & 15;
                float dm = fmaf(mask[cells[j] * 64 + p * 4 + sub], MASKV, dr[k]);
                bool c0_ = dm < d0, c1_ = dm < d1, c2_ = dm < d2;
                d2 = c1_ ? d1 : (c2_ ? dm : d2);
                i2 = c1_ ? i1 : (c2_ ? k  : i2);
                d1 = c0_ ? d0 : (c1_ ? dm : d1);
                i1 = c0_ ? i0 : (c1_ ? k  : i1);
                d0 = c0_ ? dm : d0;
                i0 = c0_ ? k  : i0;
            }
            float v0 = fmaxf(d0, CUT), v1 = fmaxf(d1, CUT), v2 = fmaxf(d2, CUT);
            float w0 = 1.0f / (v0 * v0);
            float w1 = 1.0f / (v1 * v1);
            float w2 = 1.0f / (v2 * v2);
            float inv = 1.0f / (w0 + w1 + w2);
            float xa = x[cells[i0 >> 4] * 64 + (i0 & 15) * 4 + sub];
            float xb = x[cells[i1 >> 4] * 64 + (i1 & 15) * 4 + sub];
            float xd = x[cells[i2 >> 4] * 64 + (i2 & 15) * 4 + sub];
            out[row * 4 + sub] = (xa * w0 + xb * w1 + xd * w2) * inv;
        }
    }
}

extern "C" void kernel_launch(void* const* d_in, const int* in_sizes, int n_in,
                              void* d_out, int out_size, void* d_ws, size_t ws_size,
                              hipStream_t stream) {
    const float* x      = (const float*)d_in[0];   // 262144 f32
    const float* mask   = (const float*)d_in[1];   // 262144 f32
    const float* dist   = (const float*)d_in[2];   // 9437184 f32
    const int*   nh_idx = (const int*)d_in[3];     // 36864 i32
    float*       out    = (float*)d_out;           // 262144 f32

    // 65536 rows x 8 lanes/row = 524288 threads; 32 rows (2 cells) per block.
    interp_kernel<<<(N_L * NT) / 32, 256, 0, stream>>>(x, mask, dist,
                                                       nh_idx, out);
}